// Round 6
// baseline (282.759 us; speedup 1.0000x reference)
//
#include <hip/hip_runtime.h>
#include <hip/hip_bf16.h>

#define BB 8
#define NN 1024
#define MM 2048
#define DD 1024

typedef __attribute__((ext_vector_type(8))) __bf16 bfrag8;  // 8 bf16 = 4 VGPRs
typedef __attribute__((ext_vector_type(4))) float ffrag4;   // 4 fp32 acc

__device__ __forceinline__ unsigned short f2bf(float f) {
  union { float f; unsigned u; } x; x.f = f;
  unsigned r = x.u + 0x7FFFu + ((x.u >> 16) & 1u);
  return (unsigned short)(r >> 16);
}

// async global->LDS, 16B per lane; LDS dst = wave-uniform base + lane*16
__device__ __forceinline__ void gload_lds16(const unsigned short* g, unsigned short* l) {
  __builtin_amdgcn_global_load_lds(
      (const __attribute__((address_space(1))) void*)g,
      (__attribute__((address_space(3))) void*)l, 16, 0, 0);
}

#define SCHED0() __builtin_amdgcn_sched_barrier(0)
#define MFMA16x16x32 __builtin_amdgcn_mfma_f32_16x16x32_bf16

// ---------------------------------------------------------------------------
// stage one 128x64-bf16 tile (16 KB): 2 global_load_lds insts per wave.
// LDS: row-linear [128][64] ushorts; 16B chunk c holds logical chunk
// c ^ (row&7) (conflict-free ds_read_b128 swizzle via pre-swizzled source).
// ---------------------------------------------------------------------------
__device__ __forceinline__ void stage_half(const unsigned short* gbase, int ldk,
                                           unsigned short* ldst,
                                           int w, int r0, int slog) {
  const unsigned short* g = gbase + (size_t)(w * 8 + r0) * ldk + slog;
  gload_lds16(g, ldst + w * 512);                       // rows  0..63
  gload_lds16(g + (size_t)64 * ldk, ldst + 4096 + w * 512);  // rows 64..127
}

// ===========================================================================
// ta_prep: fused {cvtQ | trans | zero-rowsum} by block range.
// ===========================================================================
#define TSTR 68
__global__ __launch_bounds__(256) void ta_prep(
    const float* __restrict__ Q, const float* __restrict__ V,
    unsigned short* __restrict__ Qbf,
    unsigned short* __restrict__ Kbf, unsigned short* __restrict__ VT,
    float* __restrict__ sums)
{
  __shared__ unsigned short Tls[64 * TSTR];
  const int bid = blockIdx.x;
  const int t = threadIdx.x;

  if (bid < 4096) {
    int tt = bid * 256 + t;
    const float4* src = reinterpret_cast<const float4*>(Q) + tt * 2;
    float4 a = src[0], b = src[1];
    ushort4 lo = { f2bf(a.x), f2bf(a.y), f2bf(a.z), f2bf(a.w) };
    ushort4 hi = { f2bf(b.x), f2bf(b.y), f2bf(b.z), f2bf(b.w) };
    ushort4* dst = reinterpret_cast<ushort4*>(Qbf) + tt * 2;
    dst[0] = lo; dst[1] = hi;
  } else if (bid < 8192) {
    const int id = bid - 4096;
    const int dt = id & 15;
    const int mt = (id >> 4) & 31;
    const int b  = id >> 9;

    const float* Vb = V + (size_t)b * MM * DD + (size_t)(mt * 64) * DD + dt * 64;
#pragma unroll
    for (int it = 0; it < 4; ++it) {
      int slot = t + 256 * it;
      int row  = slot >> 4;
      int c4   = slot & 15;
      float4 a = *reinterpret_cast<const float4*>(Vb + (size_t)row * DD + c4 * 4);
      ushort4 h = { f2bf(a.x), f2bf(a.y), f2bf(a.z), f2bf(a.w) };
      *reinterpret_cast<ushort4*>(&Tls[row * TSTR + c4 * 4]) = h;
    }
    __syncthreads();

    unsigned short* Kb = Kbf + (size_t)b * MM * DD + (size_t)(mt * 64) * DD + dt * 64;
    unsigned short* Vt = VT  + (size_t)b * DD * MM + (size_t)(dt * 64) * MM + mt * 64;
#pragma unroll
    for (int it = 0; it < 4; ++it) {
      int slot = t + 256 * it;
      int row  = slot >> 4;
      int c4   = slot & 15;
      *reinterpret_cast<ushort4*>(Kb + (size_t)row * DD + c4 * 4) =
          *reinterpret_cast<const ushort4*>(&Tls[row * TSTR + c4 * 4]);
      ushort4 tv = { Tls[(c4 * 4 + 0) * TSTR + row],
                     Tls[(c4 * 4 + 1) * TSTR + row],
                     Tls[(c4 * 4 + 2) * TSTR + row],
                     Tls[(c4 * 4 + 3) * TSTR + row] };
      *reinterpret_cast<ushort4*>(Vt + (size_t)row * MM + c4 * 4) = tv;
    }
  } else {
    int tt = (bid - 8192) * 256 + t;
    sums[tt] = 0.0f;
  }
}

// --- zero rowsums (tier B only) ---------------------------------------------
__global__ void ta_zero(float* __restrict__ sums) {
  int t = blockIdx.x * 256 + threadIdx.x;
  if (t < BB * NN) sums[t] = 0.0f;
}

// ===========================================================================
// GEMM1: 128x128 tile, BK=64, 2 buffers (64 KB LDS -> 2 blocks/CU), R3-style
// schedule: frag reads -> lgkm drain -> certify barrier -> MFMA h1 ->
// stage kt+2 into freed buffer -> MFMA h2 -> counted vmcnt(4) -> barrier.
// e = exp(QK/32 + bias) -> bf16 Ebf + rowsum.  grid (MM/128, NN/128, BB).
// ===========================================================================
__global__ __launch_bounds__(512, 4) void ta_gemm1x(
    const unsigned short* __restrict__ Q,   // bf16 (B,N,D)
    const unsigned short* __restrict__ K,   // bf16 (B,M,D)
    const float* __restrict__ sigma,
    const int* __restrict__ lens,
    unsigned short* __restrict__ Ebf,       // bf16 (B,N,M)
    float* __restrict__ rowsum)
{
  // grid (16,8,8) = 1024 blocks; bijective XCD-chunk swizzle (chunk 128).
  // Consecutive wids share (b,bi) -> Q-panel L2 reuse within an XCD.
  const int lin = blockIdx.x + 16 * (blockIdx.y + 8 * blockIdx.z);
  const int wid = (lin & 7) * 128 + (lin >> 3);
  const int bj = wid & 15, bi = (wid >> 4) & 7, b = wid >> 7;

  const int t = threadIdx.x;
  const int lane = t & 63, w = t >> 6;
  const int wr = w >> 2, wc = w & 3;       // 2 x 4 wave grid; wave tile 64x32
  __shared__ unsigned short S[32768];      // 64 KB: 2 bufs x (A 8192 | B 8192)

  const unsigned short* Qb = Q + (size_t)b * NN * DD + (size_t)(bi * 128) * DD;
  const unsigned short* Kb = K + (size_t)b * MM * DD + (size_t)(bj * 128) * DD;

  const int r  = lane & 15, qd = lane >> 4;
  const int r0 = (lane >> 3) & 7;
  const int slog = ((lane & 7) ^ r0) << 3;        // staging source chunk (inv swz)
  const int cs0 = ((qd)     ^ (r & 7)) << 3;      // frag read chunk, kstep 0
  const int cs1 = ((4 + qd) ^ (r & 7)) << 3;      // frag read chunk, kstep 1

  ffrag4 acc[4][2] = {};

  // ---- prologue: stage K-tiles 0,1 into bufs 0,1 (4 gloads/wave each) ----
  {
    stage_half(Qb,      DD, &S[0],             w, r0, slog);
    stage_half(Kb,      DD, &S[8192],          w, r0, slog);
    stage_half(Qb + 64, DD, &S[16384],         w, r0, slog);
    stage_half(Kb + 64, DD, &S[16384 + 8192],  w, r0, slog);
    asm volatile("s_waitcnt vmcnt(4)" ::: "memory");   // tile 0 landed
    __builtin_amdgcn_s_barrier();
  }

  for (int kt = 0; kt < 16; ++kt) {
    unsigned short* Tb = &S[(kt & 1) * 16384];
    bfrag8 af[4][2], bf[2][2];

    // ---- frag reads (12 x ds_read_b128) ----
#pragma unroll
    for (int mi = 0; mi < 4; ++mi) {
      const unsigned short* a = &Tb[(wr * 64 + mi * 16 + r) * 64];
      af[mi][0] = *reinterpret_cast<const bfrag8*>(a + cs0);
      af[mi][1] = *reinterpret_cast<const bfrag8*>(a + cs1);
    }
#pragma unroll
    for (int nj = 0; nj < 2; ++nj) {
      const unsigned short* bp = &Tb[8192 + (wc * 32 + nj * 16 + r) * 64];
      bf[nj][0] = *reinterpret_cast<const bfrag8*>(bp + cs0);
      bf[nj][1] = *reinterpret_cast<const bfrag8*>(bp + cs1);
    }

    // ---- certify all reads (drain BEFORE barrier) ----
    asm volatile("s_waitcnt lgkmcnt(0)" ::: "memory");
    SCHED0(); __builtin_amdgcn_s_barrier();

    // ---- MFMA half 1 ----
    __builtin_amdgcn_s_setprio(1);
#pragma unroll
    for (int mi = 0; mi < 2; ++mi)
#pragma unroll
      for (int nj = 0; nj < 2; ++nj) {
        acc[mi][nj] = MFMA16x16x32(af[mi][0], bf[nj][0], acc[mi][nj], 0, 0, 0);
        acc[mi][nj] = MFMA16x16x32(af[mi][1], bf[nj][1], acc[mi][nj], 0, 0, 0);
      }
    __builtin_amdgcn_s_setprio(0); SCHED0();

    // ---- stage kt+2 into THIS buffer (fully read at the barrier above) ----
    if (kt + 2 < 16) {
      const int k0 = (kt + 2) * 64;
      stage_half(Qb + k0, DD, Tb,        w, r0, slog);
      stage_half(Kb + k0, DD, Tb + 8192, w, r0, slog);
    }

    // ---- MFMA half 2 ----
    SCHED0(); __builtin_amdgcn_s_setprio(1);
#pragma unroll
    for (int mi = 2; mi < 4; ++mi)
#pragma unroll
      for (int nj = 0; nj < 2; ++nj) {
        acc[mi][nj] = MFMA16x16x32(af[mi][0], bf[nj][0], acc[mi][nj], 0, 0, 0);
        acc[mi][nj] = MFMA16x16x32(af[mi][1], bf[nj][1], acc[mi][nj], 0, 0, 0);
      }
    __builtin_amdgcn_s_setprio(0); SCHED0();

    // counted wait: tile kt+1 resident; tile kt+2 stays in flight
    if (kt < 14)       { asm volatile("s_waitcnt vmcnt(4)" ::: "memory"); }
    else if (kt == 14) { asm volatile("s_waitcnt vmcnt(0)" ::: "memory"); }
    if (kt < 15) __builtin_amdgcn_s_barrier();
  }

  // ---- epilogue: e = exp(score + bias), bf16 store + rowsum atomics ----
  const float sg = fabsf(sigma[0]) + 1e-8f;
  const float inv2s2 = 1.0f / (2.0f * sg * sg);
  const int len = lens[b];
  unsigned short* Erow = Ebf + (size_t)b * NN * MM;
  float* sums = rowsum + (size_t)b * NN;
  const int ibase = bi * 128 + wr * 64;
  const int jbase = bj * 128 + wc * 32;
#pragma unroll
  for (int mi = 0; mi < 4; ++mi) {
#pragma unroll
    for (int v = 0; v < 4; ++v) {
      int i = ibase + mi * 16 + qd * 4 + v;
      float psum = 0.0f;
#pragma unroll
      for (int nj = 0; nj < 2; ++nj) {
        int j = jbase + nj * 16 + r;
        float e = 0.0f;
        if (j < len) {
          float dr = (float)i * (1.0f / (float)NN) - (float)j * (1.0f / (float)MM);
          float sc = acc[mi][nj][v] * 0.03125f - dr * dr * inv2s2;
          e = __expf(fminf(sc, 30.0f));
        }
        psum += e;
        Erow[(size_t)i * MM + j] = f2bf(e);
      }
      psum += __shfl_xor(psum, 1);
      psum += __shfl_xor(psum, 2);
      psum += __shfl_xor(psum, 4);
      psum += __shfl_xor(psum, 8);
      if (r == 0) atomicAdd(&sums[i], psum);
    }
  }
}

// ===========================================================================
// GEMM2: 128x128 tile, BK=64, 2 buffers (64 KB LDS -> 2 blocks/CU), same
// R3-style schedule.  O = (E @ VT^T)/rowsum; attn fp32 normalization sourced
// from the staged E tile in LDS during the 4 k-steps where kt>>2 == bd.
// grid (DD/128, NN/128, BB) = 512 blocks, 512 thr.
// ===========================================================================
__global__ __launch_bounds__(512, 4) void ta_gemm2x(
    const unsigned short* __restrict__ E,   // bf16 (B,N,M)
    const unsigned short* __restrict__ VT,  // bf16 (B,D,M)
    const float* __restrict__ rowsum,
    float* __restrict__ O,                  // fp32 (B,N,D)
    float* __restrict__ attn)               // fp32 (B,N,M)
{
  // grid (8,8,8) = 512 blocks; bijective XCD-chunk swizzle (chunk 64).
  // Consecutive wids share (b,bi) -> E-panel L2 reuse within an XCD.
  const int lin = blockIdx.x + 8 * (blockIdx.y + 8 * blockIdx.z);
  const int wid = (lin & 7) * 64 + (lin >> 3);
  const int bd = wid & 7, bi = (wid >> 3) & 7, b = wid >> 6;

  const int t = threadIdx.x;
  const int lane = t & 63, w = t >> 6;
  const int wr = w >> 2, wc = w & 3;       // 2 x 4 wave grid; wave tile 64x32
  __shared__ unsigned short S[32768];      // 64 KB: 2 bufs x (E 8192 | VT 8192)

  const unsigned short* Eb = E  + (size_t)b * NN * MM + (size_t)(bi * 128) * MM;
  const unsigned short* Vb = VT + (size_t)b * DD * MM + (size_t)(bd * 128) * MM;

  const int r  = lane & 15, qd = lane >> 4;
  const int r0 = (lane >> 3) & 7;
  const int slog = ((lane & 7) ^ r0) << 3;
  const int cs0 = ((qd)     ^ (r & 7)) << 3;
  const int cs1 = ((4 + qd) ^ (r & 7)) << 3;

  ffrag4 acc[4][2] = {};

  // attn interleave constants
  const float* rsB = rowsum + (size_t)b * NN;
  const int arow = t >> 2;                  // 0..127
  const int lcb  = (t & 3) * 2;             // logical chunk base (0,2,4,6)
  const int apc0 = (lcb)     ^ (arow & 7);  // physical chunks in swizzled tile
  const int apc1 = (lcb + 1) ^ (arow & 7);
  const float ainv = 1.0f / fmaxf(rsB[bi * 128 + arow], 1e-30f);
  float* attnRowBase = attn + ((size_t)b * NN + bi * 128 + arow) * MM;

  // ---- prologue: stage K-tiles 0,1 into bufs 0,1 (4 gloads/wave each) ----
  {
    stage_half(Eb,      MM, &S[0],             w, r0, slog);
    stage_half(Vb,      MM, &S[8192],          w, r0, slog);
    stage_half(Eb + 64, MM, &S[16384],         w, r0, slog);
    stage_half(Vb + 64, MM, &S[16384 + 8192],  w, r0, slog);
    asm volatile("s_waitcnt vmcnt(4)" ::: "memory");   // tile 0 landed
    __builtin_amdgcn_s_barrier();
  }

  for (int kt = 0; kt < 32; ++kt) {
    unsigned short* Tb = &S[(kt & 1) * 16384];
    bfrag8 af[4][2], bf[2][2];
    const bool awin = ((kt >> 2) == bd);
    uint4 av0, av1;

    // ---- frag reads (12 x ds_read_b128) ----
#pragma unroll
    for (int mi = 0; mi < 4; ++mi) {
      const unsigned short* a = &Tb[(wr * 64 + mi * 16 + r) * 64];
      af[mi][0] = *reinterpret_cast<const bfrag8*>(a + cs0);
      af[mi][1] = *reinterpret_cast<const bfrag8*>(a + cs1);
    }
#pragma unroll
    for (int nj = 0; nj < 2; ++nj) {
      const unsigned short* bp = &Tb[8192 + (wc * 32 + nj * 16 + r) * 64];
      bf[nj][0] = *reinterpret_cast<const bfrag8*>(bp + cs0);
      bf[nj][1] = *reinterpret_cast<const bfrag8*>(bp + cs1);
    }
    // attn LDS reads of the current E tile (same certify barrier as frags)
    if (awin) {
      av0 = *reinterpret_cast<const uint4*>(&Tb[arow * 64 + apc0 * 8]);
      av1 = *reinterpret_cast<const uint4*>(&Tb[arow * 64 + apc1 * 8]);
    }

    // ---- certify all reads (drain BEFORE barrier) ----
    asm volatile("s_waitcnt lgkmcnt(0)" ::: "memory");
    SCHED0(); __builtin_amdgcn_s_barrier();

    // ---- attn convert + store (VMEM stores OLDER than this step's stages) ----
    if (awin) {
      float* dst = attnRowBase + kt * 64 + lcb * 8;
      unsigned u[8] = { av0.x, av0.y, av0.z, av0.w, av1.x, av1.y, av1.z, av1.w };
      float o[16];
#pragma unroll
      for (int k2 = 0; k2 < 8; ++k2) {
        union { unsigned u; float f; } lo, hi;
        lo.u = u[k2] << 16; hi.u = u[k2] & 0xFFFF0000u;
        o[2 * k2]     = lo.f * ainv;
        o[2 * k2 + 1] = hi.f * ainv;
      }
      float4* d4 = reinterpret_cast<float4*>(dst);
      float4 f0 = { o[0],  o[1],  o[2],  o[3]  };
      float4 f1 = { o[4],  o[5],  o[6],  o[7]  };
      float4 f2 = { o[8],  o[9],  o[10], o[11] };
      float4 f3 = { o[12], o[13], o[14], o[15] };
      d4[0] = f0; d4[1] = f1; d4[2] = f2; d4[3] = f3;
    }
    SCHED0();

    // ---- MFMA half 1 ----
    __builtin_amdgcn_s_setprio(1);
#pragma unroll
    for (int mi = 0; mi < 2; ++mi)
#pragma unroll
      for (int nj = 0; nj < 2; ++nj) {
        acc[mi][nj] = MFMA16x16x32(af[mi][0], bf[nj][0], acc[mi][nj], 0, 0, 0);
        acc[mi][nj] = MFMA16x16x32(af[mi][1], bf[nj][1], acc[mi][nj], 0, 0, 0);
      }
    __builtin_amdgcn_s_setprio(0); SCHED0();

    // ---- stage kt+2 into THIS buffer (fully read at the barrier above) ----
    if (kt + 2 < 32) {
      const int k0 = (kt + 2) * 64;
      stage_half(Eb + k0, MM, Tb,        w, r0, slog);
      stage_half(Vb + k0, MM, Tb + 8192, w, r0, slog);
    }

    // ---- MFMA half 2 ----
    SCHED0(); __builtin_amdgcn_s_setprio(1);
#pragma unroll
    for (int mi = 2; mi < 4; ++mi)
#pragma unroll
      for (int nj = 0; nj < 2; ++nj) {
        acc[mi][nj] = MFMA16x16x32(af[mi][0], bf[nj][0], acc[mi][nj], 0, 0, 0);
        acc[mi][nj] = MFMA16x16x32(af[mi][1], bf[nj][1], acc[mi][nj], 0, 0, 0);
      }
    __builtin_amdgcn_s_setprio(0); SCHED0();

    // counted wait: tile kt+1 resident; tile kt+2 stays in flight
    if (kt < 30)       { asm volatile("s_waitcnt vmcnt(4)" ::: "memory"); }
    else if (kt == 30) { asm volatile("s_waitcnt vmcnt(0)" ::: "memory"); }
    if (kt < 31) __builtin_amdgcn_s_barrier();
  }

  // ---- epilogue: O = acc / rowsum ----
  float* Ob = O + (size_t)b * NN * DD;
  const int ibase = bi * 128 + wr * 64;
  const int dbase = bd * 128 + wc * 32;
#pragma unroll
  for (int mi = 0; mi < 4; ++mi) {
#pragma unroll
    for (int v = 0; v < 4; ++v) {
      int i = ibase + mi * 16 + qd * 4 + v;
      float inv = 1.0f / fmaxf(rsB[i], 1e-30f);
#pragma unroll
      for (int nj = 0; nj < 2; ++nj) {
        int d = dbase + nj * 16 + r;
        Ob[(size_t)i * DD + d] = acc[mi][nj][v] * inv;
      }
    }
  }
}

// ===========================================================================
// Tier B fallback (unchanged; needs only 32 KB ws)
// ===========================================================================
#define LDA 40
__global__ __launch_bounds__(256) void tb_gemm1e(
    const float* __restrict__ Q, const float* __restrict__ K,
    const float* __restrict__ sigma, const int* __restrict__ lens,
    float* __restrict__ attn, float* __restrict__ rowsum)
{
  const int bj = blockIdx.x, bi = blockIdx.y, b = blockIdx.z;
  const int t = threadIdx.x;
  const int lane = t & 63;
  const int w = t >> 6;
  const int wi = w >> 1, wj = w & 1;
  __shared__ unsigned short Als[128 * LDA];
  __shared__ unsigned short Bls[128 * LDA];
  const float* Qb = Q + (size_t)b * NN * DD + (size_t)(bi * 128) * DD;
  const float* Kb = K + (size_t)b * MM * DD + (size_t)(bj * 128) * DD;
  ffrag4 acc[4][4] = {};
  const int r = lane & 15;
  const int koff = (lane >> 4) * 8;
  for (int k0 = 0; k0 < DD; k0 += 32) {
#pragma unroll
    for (int it = 0; it < 4; ++it) {
      int slot = t + 256 * it;
      int row = slot >> 3, c4 = slot & 7;
      float4 qa = *reinterpret_cast<const float4*>(Qb + (size_t)row * DD + k0 + c4 * 4);
      float4 ka = *reinterpret_cast<const float4*>(Kb + (size_t)row * DD + k0 + c4 * 4);
      ushort4 qh = { f2bf(qa.x), f2bf(qa.y), f2bf(qa.z), f2bf(qa.w) };
      ushort4 kh = { f2bf(ka.x), f2bf(ka.y), f2bf(ka.z), f2bf(ka.w) };
      *reinterpret_cast<ushort4*>(&Als[row * LDA + c4 * 4]) = qh;
      *reinterpret_cast<ushort4*>(&Bls[row * LDA + c4 * 4]) = kh;
    }
    __syncthreads();
    bfrag8 af[4], bf[4];
#pragma unroll
    for (int ti = 0; ti < 4; ++ti)
      af[ti] = *reinterpret_cast<const bfrag8*>(&Als[(wi * 64 + ti * 16 + r) * LDA + koff]);
#pragma unroll
    for (int tj = 0; tj < 4; ++tj)
      bf[tj] = *reinterpret_cast<const bfrag8*>(&Bls[(wj * 64 + tj * 16 + r) * LDA + koff]);
#pragma unroll
    for (int ti = 0; ti < 4; ++ti)
#pragma unroll
      for (int tj = 0; tj < 4; ++tj)
        acc[ti][tj] = MFMA16x16x32(af[ti], bf[tj], acc[ti][tj], 0, 0, 0);
    __syncthreads();
  }
  const float s = fabsf(sigma[0]) + 1e-8f;
  const float inv2s2 = 1.0f / (2.0f * s * s);
  const int len = lens[b];
  float* Prow = attn + (size_t)b * NN * MM;
  float* sums = rowsum + (size_t)b * NN;
  const int ibase = bi * 128 + wi * 64;
  const int jbase = bj * 128 + wj * 64;
  const int quad = lane >> 4;
#pragma unroll
  for (int ti = 0; ti < 4; ++ti) {
#pragma unroll
    for (int v = 0; v < 4; ++v) {
      int i = ibase + ti * 16 + quad * 4 + v;
      float psum = 0.0f;
#pragma unroll
      for (int tj = 0; tj < 4; ++tj) {
        int j = jbase + tj * 16 + r;
        float e = 0.0f;
        if (j < len) {
          float dr = (float)i * (1.0f / (float)NN) - (float)j * (1.0f / (float)MM);
          float sc = acc[ti][tj][v] * 0.03125f - dr * dr * inv2s2;
          e = __expf(fminf(sc, 30.0f));
        }
        psum += e;
        Prow[(size_t)i * MM + j] = e;
      }
      psum += __shfl_xor(psum, 1);
      psum += __shfl_xor(psum, 2);
      psum += __shfl_xor(psum, 4);
      psum += __shfl_xor(psum, 8);
      if (r == 0) atomicAdd(&sums[i], psum);
    }
  }
}

__global__ __launch_bounds__(256) void tb_norm(float* __restrict__ attn,
                                               const float* __restrict__ sums) {
  int t = blockIdx.x * 256 + threadIdx.x;
  int row = t >> 9;
  const float inv = 1.0f / fmaxf(sums[row], 1e-30f);
  float4* p = reinterpret_cast<float4*>(attn) + t;
  float4 x = *p;
  x.x *= inv; x.y *= inv; x.z *= inv; x.w *= inv;
  *p = x;
}

__global__ __launch_bounds__(256) void tb_gemm2(
    const float* __restrict__ P, const float* __restrict__ V, float* __restrict__ O)
{
  const int bd = blockIdx.x, bi = blockIdx.y, b = blockIdx.z;
  const int t = threadIdx.x;
  const int lane = t & 63;
  const int w = t >> 6;
  const int wi = w >> 1, wj = w & 1;
  __shared__ unsigned short Pls[128 * LDA];
  __shared__ unsigned short Vls[128 * LDA];
  const float* Pb = P + (size_t)b * NN * MM + (size_t)(bi * 128) * MM;
  const float* Vb = V + (size_t)b * MM * DD + bd * 128;
  ffrag4 acc[4][4] = {};
  const int r = lane & 15;
  const int koff = (lane >> 4) * 8;
  const int vd = t & 127;
  const int vmb = (t >> 7) * 16;
  for (int k0 = 0; k0 < MM; k0 += 32) {
#pragma unroll
    for (int it = 0; it < 4; ++it) {
      int slot = t + 256 * it;
      int row = slot >> 3, c4 = slot & 7;
      float4 pa = *reinterpret_cast<const float4*>(Pb + (size_t)row * MM + k0 + c4 * 4);
      ushort4 ph = { f2bf(pa.x), f2bf(pa.y), f2bf(pa.z), f2bf(pa.w) };
      *reinterpret_cast<ushort4*>(&Pls[row * LDA + c4 * 4]) = ph;
    }
    union { unsigned short h[16]; uint4 q[2]; } hv;
#pragma unroll
    for (int i = 0; i < 16; ++i)
      hv.h[i] = f2bf(Vb[(size_t)(k0 + vmb + i) * DD + vd]);
    *reinterpret_cast<uint4*>(&Vls[vd * LDA + vmb]) = hv.q[0];
    *reinterpret_cast<uint4*>(&Vls[vd * LDA + vmb + 8]) = hv.q[1];
    __syncthreads();
    bfrag8 af[4], bf[4];
#pragma unroll
    for (int ti = 0; ti < 4; ++ti)
      af[ti] = *reinterpret_cast<const bfrag8*>(&Pls[(wi * 64 + ti * 16 + r) * LDA + koff]);
#pragma unroll
    for (int tj = 0; tj < 4; ++tj)
      bf[tj] = *reinterpret_cast<const bfrag8*>(&Vls[(wj * 64 + tj * 16 + r) * LDA + koff]);
#pragma unroll
    for (int ti = 0; ti < 4; ++ti)
#pragma unroll
      for (int tj = 0; tj < 4; ++tj)
        acc[ti][tj] = MFMA16x16x32(af[ti], bf[tj], acc[ti][tj], 0, 0, 0);
    __syncthreads();
  }
  float* Ob = O + (size_t)b * NN * DD;
  const int ibase = bi * 128 + wi * 64;
  const int dbase = bd * 128 + wj * 64;
#pragma unroll
  for (int ti = 0; ti < 4; ++ti) {
#pragma unroll
    for (int tj = 0; tj < 4; ++tj) {
      int d = dbase + tj * 16 + r;
#pragma unroll
      for (int v = 0; v < 4; ++v) {
        int i = ibase + ti * 16 + (lane >> 4) * 4 + v;
        Ob[(size_t)i * DD + d] = acc[ti][tj][v];
      }
    }
  }
}

// ---------------------------------------------------------------------------
extern "C" void kernel_launch(void* const* d_in, const int* in_sizes, int n_in,
                              void* d_out, int out_size, void* d_ws, size_t ws_size,
                              hipStream_t stream) {
  const float* text  = (const float*)d_in[0];
  const float* audio = (const float*)d_in[1];
  const float* sigma = (const float*)d_in[2];
  const int*   lens  = (const int*)d_in[3];

  float* out = (float*)d_out;
  float* enhanced = out;                       // B*N*D fp32
  float* attn = out + (size_t)BB * NN * DD;    // B*N*M fp32

  const size_t QBF  = (size_t)BB * NN * DD * 2;   // 16 MB
  const size_t KBF  = (size_t)BB * MM * DD * 2;   // 32 MB
  const size_t VTB  = (size_t)BB * DD * MM * 2;   // 32 MB
  const size_t EBF  = (size_t)BB * NN * MM * 2;   // 32 MB
  const size_t offQ = 65536;
  const size_t offK = offQ + QBF;
  const size_t offV = offK + KBF;
  const size_t offE = offV + VTB;
  const size_t need = offE + EBF;

  float* rowsum = (float*)d_ws;                // 32 KB @ 0

  if (ws_size >= need) {
    unsigned short* Qbf = (unsigned short*)((char*)d_ws + offQ);
    unsigned short* Kbf = (unsigned short*)((char*)d_ws + offK);
    unsigned short* VT  = (unsigned short*)((char*)d_ws + offV);
    unsigned short* Ebf = (unsigned short*)((char*)d_ws + offE);

    ta_prep<<<dim3(8224), 256, 0, stream>>>(text, audio, Qbf, Kbf, VT, rowsum);
    ta_gemm1x<<<dim3(MM / 128, NN / 128, BB), 512, 0, stream>>>(Qbf, Kbf, sigma, lens, Ebf, rowsum);
    ta_gemm2x<<<dim3(DD / 128, NN / 128, BB), 512, 0, stream>>>(Ebf, VT, rowsum, enhanced, attn);
  } else {
    ta_zero<<<dim3((BB * NN + 255) / 256), 256, 0, stream>>>(rowsum);
    tb_gemm1e<<<dim3(MM / 128, NN / 128, BB), 256, 0, stream>>>(text, audio, sigma, lens, attn, rowsum);
    tb_norm<<<dim3(BB * NN * MM / 4 / 256), 256, 0, stream>>>(attn, rowsum);
    tb_gemm2<<<dim3(DD / 128, NN / 128, BB), 256, 0, stream>>>(attn, audio, enhanced);
  }
}

// Round 7
// 260.680 us; speedup vs baseline: 1.0847x; 1.0847x over previous
//
#include <hip/hip_runtime.h>
#include <hip/hip_bf16.h>

#define BB 8
#define NN 1024
#define MM 2048
#define DD 1024

typedef __attribute__((ext_vector_type(8))) __bf16 bfrag8;  // 8 bf16 = 4 VGPRs
typedef __attribute__((ext_vector_type(4))) float ffrag4;   // 4 fp32 acc

__device__ __forceinline__ unsigned short f2bf(float f) {
  union { float f; unsigned u; } x; x.f = f;
  unsigned r = x.u + 0x7FFFu + ((x.u >> 16) & 1u);
  return (unsigned short)(r >> 16);
}

__device__ __forceinline__ unsigned pack2(unsigned short lo, unsigned short hi) {
  return (unsigned)lo | ((unsigned)hi << 16);
}

// async global->LDS, 16B per lane; LDS dst = wave-uniform base + lane*16
__device__ __forceinline__ void gload_lds16(const unsigned short* g, unsigned short* l) {
  __builtin_amdgcn_global_load_lds(
      (const __attribute__((address_space(1))) void*)g,
      (__attribute__((address_space(3))) void*)l, 16, 0, 0);
}

#define SCHED0() __builtin_amdgcn_sched_barrier(0)
#define MFMA16x16x32 __builtin_amdgcn_mfma_f32_16x16x32_bf16

// ---------------------------------------------------------------------------
// stage one 128x64-bf16 half-tile (16 KB): 2 global_load_lds insts per wave.
// LDS layout: row-linear [128][64] ushorts, 16B chunk c holds logical chunk
// c ^ (row&7) (conflict-free ds_read_b128 swizzle, applied on global source).
// ---------------------------------------------------------------------------
__device__ __forceinline__ void stage_half(const unsigned short* gbase, int ldk,
                                           unsigned short* ldst,
                                           int w, int r0, int slog) {
  const unsigned short* g = gbase + (size_t)(w * 8 + r0) * ldk + slog;
  gload_lds16(g, ldst + w * 512);                       // rows  0..63
  gload_lds16(g + (size_t)64 * ldk, ldst + 4096 + w * 512);  // rows 64..127
}

// ===========================================================================
// ta_prep v2: fused {cvtQ | trans | zero-rowsum} by block range.
// trans: transposed-scatter LDS (chunk-XOR swizzle, conflict-free) ->
// vectorized b128 readback; all global stores 16B.
// ===========================================================================
__global__ __launch_bounds__(256) void ta_prep(
    const float* __restrict__ Q, const float* __restrict__ V,
    unsigned short* __restrict__ Qbf,
    unsigned short* __restrict__ Kbf, unsigned short* __restrict__ VT,
    float* __restrict__ sums)
{
  __shared__ unsigned short Tls[4096];   // 64 d x 64 m bf16, chunk-swizzled
  const int bid = blockIdx.x;
  const int t = threadIdx.x;

  if (bid < 4096) {
    // ---- cvtQ: 8 elems/thread, one 16B store ----
    int tt = bid * 256 + t;
    const float4* src = reinterpret_cast<const float4*>(Q) + tt * 2;
    float4 a = src[0], b = src[1];
    uint4 o = { pack2(f2bf(a.x), f2bf(a.y)), pack2(f2bf(a.z), f2bf(a.w)),
                pack2(f2bf(b.x), f2bf(b.y)), pack2(f2bf(b.z), f2bf(b.w)) };
    *(reinterpret_cast<uint4*>(Qbf) + tt) = o;
  } else if (bid < 8192) {
    // ---- trans: audio fp32 -> Kbf (M,D bf16) + VT (D,M bf16), 64x64 tile ----
    const int id = bid - 4096;
    const int dt = id & 15;
    const int mt = (id >> 4) & 31;
    const int b  = id >> 9;

    const float* Vb = V + (size_t)b * MM * DD + (size_t)(mt * 64) * DD + dt * 64;

    // phase 1: row-major load (64B/lane), Kbf direct store (2x16B),
    // transposed scalar scatter into swizzled LDS.
    const int row  = t >> 2;          // local m (0..63)
    const int dseg = (t & 3) * 16;    // local d base
    float4 f[4];
#pragma unroll
    for (int q = 0; q < 4; ++q)
      f[q] = *reinterpret_cast<const float4*>(Vb + (size_t)row * DD + dseg + q * 4);
    unsigned short h[16];
#pragma unroll
    for (int q = 0; q < 4; ++q) {
      h[q * 4 + 0] = f2bf(f[q].x); h[q * 4 + 1] = f2bf(f[q].y);
      h[q * 4 + 2] = f2bf(f[q].z); h[q * 4 + 3] = f2bf(f[q].w);
    }
    unsigned short* Kb = Kbf + (size_t)b * MM * DD + (size_t)(mt * 64) * DD + dt * 64;
    uint4 k0 = { pack2(h[0], h[1]),  pack2(h[2], h[3]),
                 pack2(h[4], h[5]),  pack2(h[6], h[7]) };
    uint4 k1 = { pack2(h[8], h[9]),  pack2(h[10], h[11]),
                 pack2(h[12], h[13]), pack2(h[14], h[15]) };
    *reinterpret_cast<uint4*>(Kb + (size_t)row * DD + dseg)     = k0;
    *reinterpret_cast<uint4*>(Kb + (size_t)row * DD + dseg + 8) = k1;

    const int rc = row >> 3, rp = row & 7;
#pragma unroll
    for (int j = 0; j < 16; ++j) {
      int d = dseg + j;
      Tls[d * 64 + ((rc ^ (d >> 3)) << 3) + rp] = h[j];
    }
    __syncthreads();

    // phase 2: vectorized b128 readback (d-major), 2x16B VT stores.
    const int dl   = t >> 2;          // local d (0..63)
    const int mseg = (t & 3) * 16;    // local m base
    unsigned short* Vt = VT + (size_t)b * DD * MM + (size_t)(dt * 64) * MM + mt * 64;
#pragma unroll
    for (int s = 0; s < 2; ++s) {
      int mc  = (mseg >> 3) + s;
      int pos = mc ^ (dl >> 3);
      uint4 v = *reinterpret_cast<const uint4*>(&Tls[dl * 64 + (pos << 3)]);
      *reinterpret_cast<uint4*>(Vt + (size_t)dl * MM + mseg + s * 8) = v;
    }
  } else {
    // ---- zero rowsum ----
    int tt = (bid - 8192) * 256 + t;
    sums[tt] = 0.0f;
  }
}

// --- zero rowsums (tier B only) ---------------------------------------------
__global__ void ta_zero(float* __restrict__ sums) {
  int t = blockIdx.x * 256 + threadIdx.x;
  if (t < BB * NN) sums[t] = 0.0f;
}

// ===========================================================================
// GEMM1: 256x256 tile, BK=64, counted-vmcnt, 3 barriers/K-step. (R3-best)
// e = exp(QK/32 + bias) -> bf16 Ebf + rowsum.  grid (MM/256, NN/256, BB).
// ===========================================================================
__global__ __launch_bounds__(512, 2) void ta_gemm1x(
    const unsigned short* __restrict__ Q,   // bf16 (B,N,D)
    const unsigned short* __restrict__ K,   // bf16 (B,M,D)
    const float* __restrict__ sigma,
    const int* __restrict__ lens,
    unsigned short* __restrict__ Ebf,       // bf16 (B,N,M)
    float* __restrict__ rowsum)
{
  // grid (8,4,8): linear id -> bijective XCD-chunk swizzle (256 = 8 XCD x 32)
  const int lin = blockIdx.x + 8 * (blockIdx.y + 4 * blockIdx.z);
  const int wid = (lin & 7) * 32 + (lin >> 3);
  const int bj = wid & 7, bi = (wid >> 3) & 3, b = wid >> 5;

  const int t = threadIdx.x;
  const int lane = t & 63, w = t >> 6;
  const int wr = w >> 2, wc = w & 3;       // 2 x 4 wave grid; wave tile 128x64
  __shared__ unsigned short S[65536];      // 128 KB

  const unsigned short* Qb = Q + (size_t)b * NN * DD + (size_t)(bi * 256) * DD;
  const unsigned short* Kb = K + (size_t)b * MM * DD + (size_t)(bj * 256) * DD;

  const int r  = lane & 15, qd = lane >> 4;
  const int r0 = (lane >> 3) & 7;
  const int slog = ((lane & 7) ^ r0) << 3;        // staging source chunk (inverse swz)
  const int cs0 = ((qd)     ^ (r & 7)) << 3;      // frag read chunk, kstep 0
  const int cs1 = ((4 + qd) ^ (r & 7)) << 3;      // frag read chunk, kstep 1

  ffrag4 acc[8][4] = {};

  // ---- prologue: stage K-tiles 0 and 1 (8 insts/wave each) ----
  {
    unsigned short* T0 = &S[0];
    stage_half(Qb,                        DD, T0,          w, r0, slog);
    stage_half(Qb + (size_t)128 * DD,     DD, T0 + 8192,   w, r0, slog);
    stage_half(Kb,                        DD, T0 + 16384,  w, r0, slog);
    stage_half(Kb + (size_t)128 * DD,     DD, T0 + 24576,  w, r0, slog);
    unsigned short* T1 = &S[32768];
    stage_half(Qb + 64,                    DD, T1,          w, r0, slog);
    stage_half(Qb + (size_t)128 * DD + 64, DD, T1 + 8192,   w, r0, slog);
    stage_half(Kb + 64,                    DD, T1 + 16384,  w, r0, slog);
    stage_half(Kb + (size_t)128 * DD + 64, DD, T1 + 24576,  w, r0, slog);
    asm volatile("s_waitcnt vmcnt(8)" ::: "memory");
    __builtin_amdgcn_s_barrier();
  }

#pragma unroll 2
  for (int kt = 0; kt < 16; ++kt) {
    const int p = kt & 1;
    unsigned short* Ab = &S[p * 32768 + wr * 8192];
    unsigned short* Bb = &S[p * 32768 + 16384 + (wc >> 1) * 8192];
    const int brb = (wc & 1) * 64;
    bfrag8 af[4][2], bf0[2][2], bf1[2][2];

    // ---- body0: read af[0..3] + bf0; MFMA Q00 (own-drain only, no barrier) ----
#pragma unroll
    for (int mi = 0; mi < 4; ++mi) {
      const unsigned short* a = &Ab[(mi * 16 + r) * 64];
      af[mi][0] = *reinterpret_cast<const bfrag8*>(a + cs0);
      af[mi][1] = *reinterpret_cast<const bfrag8*>(a + cs1);
    }
#pragma unroll
    for (int jj = 0; jj < 2; ++jj) {
      const unsigned short* bp = &Bb[(brb + jj * 16 + r) * 64];
      bf0[jj][0] = *reinterpret_cast<const bfrag8*>(bp + cs0);
      bf0[jj][1] = *reinterpret_cast<const bfrag8*>(bp + cs1);
    }
    asm volatile("s_waitcnt lgkmcnt(0)" ::: "memory");
    SCHED0(); __builtin_amdgcn_s_setprio(1);
#pragma unroll
    for (int mi = 0; mi < 4; ++mi)
#pragma unroll
      for (int jj = 0; jj < 2; ++jj) {
        acc[mi][jj] = MFMA16x16x32(af[mi][0], bf0[jj][0], acc[mi][jj], 0, 0, 0);
        acc[mi][jj] = MFMA16x16x32(af[mi][1], bf0[jj][1], acc[mi][jj], 0, 0, 0);
      }
    __builtin_amdgcn_s_setprio(0); SCHED0();

    // ---- body1: read bf1; certify-B barrier (drain BEFORE barrier); MFMA Q01 ----
#pragma unroll
    for (int jj = 0; jj < 2; ++jj) {
      const unsigned short* bp = &Bb[(brb + (2 + jj) * 16 + r) * 64];
      bf1[jj][0] = *reinterpret_cast<const bfrag8*>(bp + cs0);
      bf1[jj][1] = *reinterpret_cast<const bfrag8*>(bp + cs1);
    }
    asm volatile("s_waitcnt lgkmcnt(0)" ::: "memory");
    SCHED0(); __builtin_amdgcn_s_barrier();
    __builtin_amdgcn_s_setprio(1);
#pragma unroll
    for (int mi = 0; mi < 4; ++mi)
#pragma unroll
      for (int jj = 0; jj < 2; ++jj) {
        acc[mi][2 + jj] = MFMA16x16x32(af[mi][0], bf1[jj][0], acc[mi][2 + jj], 0, 0, 0);
        acc[mi][2 + jj] = MFMA16x16x32(af[mi][1], bf1[jj][1], acc[mi][2 + jj], 0, 0, 0);
      }
    __builtin_amdgcn_s_setprio(0); SCHED0();

    // ---- body2: read af[4..7]; stage B(kt+2) (B fully read at body1 barrier);
    //      certify-A barrier; MFMA Q11 ----
#pragma unroll
    for (int mi = 0; mi < 4; ++mi) {
      const unsigned short* a = &Ab[((mi + 4) * 16 + r) * 64];
      af[mi][0] = *reinterpret_cast<const bfrag8*>(a + cs0);
      af[mi][1] = *reinterpret_cast<const bfrag8*>(a + cs1);
    }
    if (kt + 2 < 16) {
      unsigned short* Dst = &S[p * 32768 + 16384];
      stage_half(Kb + (kt + 2) * 64,                    DD, Dst,        w, r0, slog);
      stage_half(Kb + (size_t)128 * DD + (kt + 2) * 64, DD, Dst + 8192, w, r0, slog);
    }
    asm volatile("s_waitcnt lgkmcnt(0)" ::: "memory");
    SCHED0(); __builtin_amdgcn_s_barrier();
    __builtin_amdgcn_s_setprio(1);
#pragma unroll
    for (int mi = 0; mi < 4; ++mi)
#pragma unroll
      for (int jj = 0; jj < 2; ++jj) {
        acc[4 + mi][2 + jj] = MFMA16x16x32(af[mi][0], bf1[jj][0], acc[4 + mi][2 + jj], 0, 0, 0);
        acc[4 + mi][2 + jj] = MFMA16x16x32(af[mi][1], bf1[jj][1], acc[4 + mi][2 + jj], 0, 0, 0);
      }
    __builtin_amdgcn_s_setprio(0); SCHED0();

    // ---- body3: stage A(kt+2) (A fully read at body2 barrier); MFMA Q10 ----
    if (kt + 2 < 16) {
      unsigned short* Dst = &S[p * 32768];
      stage_half(Qb + (kt + 2) * 64,                    DD, Dst,        w, r0, slog);
      stage_half(Qb + (size_t)128 * DD + (kt + 2) * 64, DD, Dst + 8192, w, r0, slog);
    }
    SCHED0(); __builtin_amdgcn_s_setprio(1);
#pragma unroll
    for (int mi = 0; mi < 4; ++mi)
#pragma unroll
      for (int jj = 0; jj < 2; ++jj) {
        acc[4 + mi][jj] = MFMA16x16x32(af[mi][0], bf0[jj][0], acc[4 + mi][jj], 0, 0, 0);
        acc[4 + mi][jj] = MFMA16x16x32(af[mi][1], bf0[jj][1], acc[4 + mi][jj], 0, 0, 0);
      }
    __builtin_amdgcn_s_setprio(0); SCHED0();
    if (kt + 2 < 16)      { asm volatile("s_waitcnt vmcnt(8)" ::: "memory"); }
    else if (kt + 1 < 16) { asm volatile("s_waitcnt vmcnt(0)" ::: "memory"); }
    __builtin_amdgcn_s_barrier();
  }

  // ---- epilogue: e = exp(score + bias), bf16 store + rowsum atomics ----
  const float sg = fabsf(sigma[0]) + 1e-8f;
  const float inv2s2 = 1.0f / (2.0f * sg * sg);
  const int len = lens[b];
  unsigned short* Erow = Ebf + (size_t)b * NN * MM;
  float* sums = rowsum + (size_t)b * NN;
  const int ibase = bi * 256 + wr * 128;
  const int jbase = bj * 256 + wc * 64;
#pragma unroll
  for (int mi = 0; mi < 8; ++mi) {
#pragma unroll
    for (int v = 0; v < 4; ++v) {
      int i = ibase + mi * 16 + qd * 4 + v;
      float psum = 0.0f;
#pragma unroll
      for (int nj = 0; nj < 4; ++nj) {
        int j = jbase + nj * 16 + r;
        float e = 0.0f;
        if (j < len) {
          float dr = (float)i * (1.0f / (float)NN) - (float)j * (1.0f / (float)MM);
          float sc = acc[mi][nj][v] * 0.03125f - dr * dr * inv2s2;
          e = __expf(fminf(sc, 30.0f));
        }
        psum += e;
        Erow[(size_t)i * MM + j] = f2bf(e);
      }
      psum += __shfl_xor(psum, 1);
      psum += __shfl_xor(psum, 2);
      psum += __shfl_xor(psum, 4);
      psum += __shfl_xor(psum, 8);
      if (r == 0) atomicAdd(&sums[i], psum);
    }
  }
}

// ===========================================================================
// GEMM2: 128x256 tile, BK=64, counted-vmcnt, 2 barriers/K-step. (R3-best)
// O = (E @ VT^T)/rowsum; attn fp32 slice normalization INTERLEAVED into the
// k-loop (chunk load at even kt, convert+store at odd kt).
// grid (DD/256, NN/128, BB), 512 thr.  XCD-chunked swizzle.
// ===========================================================================
__global__ __launch_bounds__(512, 2) void ta_gemm2x(
    const unsigned short* __restrict__ E,   // bf16 (B,N,M)
    const unsigned short* __restrict__ VT,  // bf16 (B,D,M)
    const float* __restrict__ rowsum,
    float* __restrict__ O,                  // fp32 (B,N,D)
    float* __restrict__ attn)               // fp32 (B,N,M)
{
  // grid (4,8,8): linear id -> bijective XCD-chunk swizzle; bd fastest in wid
  const int lin = blockIdx.x + 4 * (blockIdx.y + 8 * blockIdx.z);
  const int wid = (lin & 7) * 32 + (lin >> 3);
  const int bd = wid & 3, bi = (wid >> 2) & 7, b = wid >> 5;

  const int t = threadIdx.x;
  const int lane = t & 63, w = t >> 6;
  const int wr = w >> 2, wc = w & 3;       // 2 x 4 wave grid; wave tile 64x64
  __shared__ unsigned short S[49152];      // 96 KB

  const unsigned short* Eb = E  + (size_t)b * NN * MM + (size_t)(bi * 128) * MM;
  const unsigned short* Vb = VT + (size_t)b * DD * MM + (size_t)(bd * 256) * MM;

  const int r  = lane & 15, qd = lane >> 4;
  const int r0 = (lane >> 3) & 7;
  const int slog = ((lane & 7) ^ r0) << 3;
  const int cs0 = ((qd)     ^ (r & 7)) << 3;
  const int cs1 = ((4 + qd) ^ (r & 7)) << 3;

  ffrag4 acc[4][4] = {};

  // attn interleave state
  const float* rsB = rowsum + (size_t)b * NN;
  const float* rsT = rsB + bi * 128;
  float* attnB = attn + ((size_t)b * NN + bi * 128) * MM + bd * 512;
  const unsigned short* Eslice = Eb + bd * 512;
  uint4 ax = {0, 0, 0, 0};
  float ainv = 0.0f;
  int arow = 0, acol = 0;

  // ---- prologue: stage K-tiles 0 and 1 (6 insts/wave each) ----
  {
    stage_half(Eb,                        MM, &S[0],     w, r0, slog);
    stage_half(Vb,                        MM, &S[8192],  w, r0, slog);
    stage_half(Vb + (size_t)128 * MM,     MM, &S[16384], w, r0, slog);
    stage_half(Eb + 64,                    MM, &S[24576],         w, r0, slog);
    stage_half(Vb + 64,                    MM, &S[24576 + 8192],  w, r0, slog);
    stage_half(Vb + (size_t)128 * MM + 64, MM, &S[24576 + 16384], w, r0, slog);
    asm volatile("s_waitcnt vmcnt(6)" ::: "memory");
    __builtin_amdgcn_s_barrier();
  }

#pragma unroll 2
  for (int kt = 0; kt < 32; ++kt) {
    const int p = kt & 1;
    unsigned short* Ab = &S[p * 24576];
    unsigned short* Bb = &S[p * 24576 + 8192 + (wc >> 1) * 8192];
    const int arb = wr * 64;
    const int brb = (wc & 1) * 64;
    bfrag8 af[4][2], bf[4][2];

    // ---- read ALL fragments for this K-step (16 x ds_read_b128) ----
#pragma unroll
    for (int mi = 0; mi < 4; ++mi) {
      const unsigned short* a = &Ab[(arb + mi * 16 + r) * 64];
      af[mi][0] = *reinterpret_cast<const bfrag8*>(a + cs0);
      af[mi][1] = *reinterpret_cast<const bfrag8*>(a + cs1);
    }
#pragma unroll
    for (int nj = 0; nj < 4; ++nj) {
      const unsigned short* bp = &Bb[(brb + nj * 16 + r) * 64];
      bf[nj][0] = *reinterpret_cast<const bfrag8*>(bp + cs0);
      bf[nj][1] = *reinterpret_cast<const bfrag8*>(bp + cs1);
    }

    // ---- interleaved attn normalization (pure-memory, hidden under MFMA) ----
    if ((kt & 1) == 0) {
      int it = kt >> 1;
      int c = t + it * 512;
      arow = c >> 6;                 // wave-uniform: w + it*8
      acol = (c & 63) * 8;
      ax = *reinterpret_cast<const uint4*>(Eslice + (size_t)arow * MM + acol);
      ainv = 1.0f / fmaxf(rsT[arow], 1e-30f);
    } else {
      unsigned u[4] = { ax.x, ax.y, ax.z, ax.w };
      float o[8];
#pragma unroll
      for (int k2 = 0; k2 < 4; ++k2) {
        union { unsigned u; float f; } lo, hi;
        lo.u = u[k2] << 16; hi.u = u[k2] & 0xFFFF0000u;
        o[2 * k2]     = lo.f * ainv;
        o[2 * k2 + 1] = hi.f * ainv;
      }
      float4* dst = reinterpret_cast<float4*>(attnB + (size_t)arow * MM + acol);
      float4 f0 = { o[0], o[1], o[2], o[3] };
      float4 f1 = { o[4], o[5], o[6], o[7] };
      dst[0] = f0; dst[1] = f1;
    }

    // ---- certify all reads (drain BEFORE barrier), then MFMA half 1 ----
    asm volatile("s_waitcnt lgkmcnt(0)" ::: "memory");
    SCHED0(); __builtin_amdgcn_s_barrier();
    __builtin_amdgcn_s_setprio(1);
#pragma unroll
    for (int mi = 0; mi < 2; ++mi)
#pragma unroll
      for (int nj = 0; nj < 4; ++nj) {
        acc[mi][nj] = MFMA16x16x32(af[mi][0], bf[nj][0], acc[mi][nj], 0, 0, 0);
        acc[mi][nj] = MFMA16x16x32(af[mi][1], bf[nj][1], acc[mi][nj], 0, 0, 0);
      }
    __builtin_amdgcn_s_setprio(0); SCHED0();

    // ---- stage kt+2 (buffer p fully read at the barrier above) ----
    if (kt + 2 < 32) {
      unsigned short* Dst = &S[p * 24576];
      stage_half(Eb + (kt + 2) * 64,                    MM, Dst,         w, r0, slog);
      stage_half(Vb + (kt + 2) * 64,                    MM, Dst + 8192,  w, r0, slog);
      stage_half(Vb + (size_t)128 * MM + (kt + 2) * 64, MM, Dst + 16384, w, r0, slog);
    }

    // ---- MFMA half 2 ----
    SCHED0(); __builtin_amdgcn_s_setprio(1);
#pragma unroll
    for (int mi = 2; mi < 4; ++mi)
#pragma unroll
      for (int nj = 0; nj < 4; ++nj) {
        acc[mi][nj] = MFMA16x16x32(af[mi][0], bf[nj][0], acc[mi][nj], 0, 0, 0);
        acc[mi][nj] = MFMA16x16x32(af[mi][1], bf[nj][1], acc[mi][nj], 0, 0, 0);
      }
    __builtin_amdgcn_s_setprio(0); SCHED0();

    if (kt + 2 < 32)      { asm volatile("s_waitcnt vmcnt(6)" ::: "memory"); }
    else if (kt + 1 < 32) { asm volatile("s_waitcnt vmcnt(0)" ::: "memory"); }
    __builtin_amdgcn_s_barrier();
  }

  // ---- epilogue: O = acc / rowsum ----
  float* Ob = O + (size_t)b * NN * DD;
  const int ibase = bi * 128 + wr * 64;
  const int dbase = bd * 256 + wc * 64;
#pragma unroll
  for (int mi = 0; mi < 4; ++mi) {
#pragma unroll
    for (int v = 0; v < 4; ++v) {
      int i = ibase + mi * 16 + qd * 4 + v;
      float inv = 1.0f / fmaxf(rsB[i], 1e-30f);
#pragma unroll
      for (int nj = 0; nj < 4; ++nj) {
        int d = dbase + nj * 16 + r;
        Ob[(size_t)i * DD + d] = acc[mi][nj][v] * inv;
      }
    }
  }
}

// ===========================================================================
// Tier B fallback (unchanged; needs only 32 KB ws)
// ===========================================================================
#define LDA 40
__global__ __launch_bounds__(256) void tb_gemm1e(
    const float* __restrict__ Q, const float* __restrict__ K,
    const float* __restrict__ sigma, const int* __restrict__ lens,
    float* __restrict__ attn, float* __restrict__ rowsum)
{
  const int bj = blockIdx.x, bi = blockIdx.y, b = blockIdx.z;
  const int t = threadIdx.x;
  const int lane = t & 63;
  const int w = t >> 6;
  const int wi = w >> 1, wj = w & 1;
  __shared__ unsigned short Als[128 * LDA];
  __shared__ unsigned short Bls[128 * LDA];
  const float* Qb = Q + (size_t)b * NN * DD + (size_t)(bi * 128) * DD;
  const float* Kb = K + (size_t)b * MM * DD + (size_t)(bj * 128) * DD;
  ffrag4 acc[4][4] = {};
  const int r = lane & 15;
  const int koff = (lane >> 4) * 8;
  for (int k0 = 0; k0 < DD; k0 += 32) {
#pragma unroll
    for (int it = 0; it < 4; ++it) {
      int slot = t + 256 * it;
      int row = slot >> 3, c4 = slot & 7;
      float4 qa = *reinterpret_cast<const float4*>(Qb + (size_t)row * DD + k0 + c4 * 4);
      float4 ka = *reinterpret_cast<const float4*>(Kb + (size_t)row * DD + k0 + c4 * 4);
      ushort4 qh = { f2bf(qa.x), f2bf(qa.y), f2bf(qa.z), f2bf(qa.w) };
      ushort4 kh = { f2bf(ka.x), f2bf(ka.y), f2bf(ka.z), f2bf(ka.w) };
      *reinterpret_cast<ushort4*>(&Als[row * LDA + c4 * 4]) = qh;
      *reinterpret_cast<ushort4*>(&Bls[row * LDA + c4 * 4]) = kh;
    }
    __syncthreads();
    bfrag8 af[4], bf[4];
#pragma unroll
    for (int ti = 0; ti < 4; ++ti)
      af[ti] = *reinterpret_cast<const bfrag8*>(&Als[(wi * 64 + ti * 16 + r) * LDA + koff]);
#pragma unroll
    for (int tj = 0; tj < 4; ++tj)
      bf[tj] = *reinterpret_cast<const bfrag8*>(&Bls[(wj * 64 + tj * 16 + r) * LDA + koff]);
#pragma unroll
    for (int ti = 0; ti < 4; ++ti)
#pragma unroll
      for (int tj = 0; tj < 4; ++tj)
        acc[ti][tj] = MFMA16x16x32(af[ti], bf[tj], acc[ti][tj], 0, 0, 0);
    __syncthreads();
  }
  const float s = fabsf(sigma[0]) + 1e-8f;
  const float inv2s2 = 1.0f / (2.0f * s * s);
  const int len = lens[b];
  float* Prow = attn + (size_t)b * NN * MM;
  float* sums = rowsum + (size_t)b * NN;
  const int ibase = bi * 128 + wi * 64;
  const int jbase = bj * 128 + wj * 64;
  const int quad = lane >> 4;
#pragma unroll
  for (int ti = 0; ti < 4; ++ti) {
#pragma unroll
    for (int v = 0; v < 4; ++v) {
      int i = ibase + ti * 16 + quad * 4 + v;
      float psum = 0.0f;
#pragma unroll
      for (int tj = 0; tj < 4; ++tj) {
        int j = jbase + tj * 16 + r;
        float e = 0.0f;
        if (j < len) {
          float dr = (float)i * (1.0f / (float)NN) - (float)j * (1.0f / (float)MM);
          float sc = acc[ti][tj][v] * 0.03125f - dr * dr * inv2s2;
          e = __expf(fminf(sc, 30.0f));
        }
        psum += e;
        Prow[(size_t)i * MM + j] = e;
      }
      psum += __shfl_xor(psum, 1);
      psum += __shfl_xor(psum, 2);
      psum += __shfl_xor(psum, 4);
      psum += __shfl_xor(psum, 8);
      if (r == 0) atomicAdd(&sums[i], psum);
    }
  }
}

__global__ __launch_bounds__(256) void tb_norm(float* __restrict__ attn,
                                               const float* __restrict__ sums) {
  int t = blockIdx.x * 256 + threadIdx.x;
  int row = t >> 9;
  const float inv = 1.0f / fmaxf(sums[row], 1e-30f);
  float4* p = reinterpret_cast<float4*>(attn) + t;
  float4 x = *p;
  x.x *= inv; x.y *= inv; x.z *= inv; x.w *= inv;
  *p = x;
}

__global__ __launch_bounds__(256) void tb_gemm2(
    const float* __restrict__ P, const float* __restrict__ V, float* __restrict__ O)
{
  const int bd = blockIdx.x, bi = blockIdx.y, b = blockIdx.z;
  const int t = threadIdx.x;
  const int lane = t & 63;
  const int w = t >> 6;
  const int wi = w >> 1, wj = w & 1;
  __shared__ unsigned short Pls[128 * LDA];
  __shared__ unsigned short Vls[128 * LDA];
  const float* Pb = P + (size_t)b * NN * MM + (size_t)(bi * 128) * MM;
  const float* Vb = V + (size_t)b * MM * DD + bd * 128;
  ffrag4 acc[4][4] = {};
  const int r = lane & 15;
  const int koff = (lane >> 4) * 8;
  const int vd = t & 127;
  const int vmb = (t >> 7) * 16;
  for (int k0 = 0; k0 < MM; k0 += 32) {
#pragma unroll
    for (int it = 0; it < 4; ++it) {
      int slot = t + 256 * it;
      int row = slot >> 3, c4 = slot & 7;
      float4 pa = *reinterpret_cast<const float4*>(Pb + (size_t)row * MM + k0 + c4 * 4);
      ushort4 ph = { f2bf(pa.x), f2bf(pa.y), f2bf(pa.z), f2bf(pa.w) };
      *reinterpret_cast<ushort4*>(&Pls[row * LDA + c4 * 4]) = ph;
    }
    union { unsigned short h[16]; uint4 q[2]; } hv;
#pragma unroll
    for (int i = 0; i < 16; ++i)
      hv.h[i] = f2bf(Vb[(size_t)(k0 + vmb + i) * DD + vd]);
    *reinterpret_cast<uint4*>(&Vls[vd * LDA + vmb]) = hv.q[0];
    *reinterpret_cast<uint4*>(&Vls[vd * LDA + vmb + 8]) = hv.q[1];
    __syncthreads();
    bfrag8 af[4], bf[4];
#pragma unroll
    for (int ti = 0; ti < 4; ++ti)
      af[ti] = *reinterpret_cast<const bfrag8*>(&Pls[(wi * 64 + ti * 16 + r) * LDA + koff]);
#pragma unroll
    for (int tj = 0; tj < 4; ++tj)
      bf[tj] = *reinterpret_cast<const bfrag8*>(&Vls[(wj * 64 + tj * 16 + r) * LDA + koff]);
#pragma unroll
    for (int ti = 0; ti < 4; ++ti)
#pragma unroll
      for (int tj = 0; tj < 4; ++tj)
        acc[ti][tj] = MFMA16x16x32(af[ti], bf[tj], acc[ti][tj], 0, 0, 0);
    __syncthreads();
  }
  float* Ob = O + (size_t)b * NN * DD;
  const int ibase = bi * 128 + wi * 64;
  const int dbase = bd * 128 + wj * 64;
#pragma unroll
  for (int ti = 0; ti < 4; ++ti) {
#pragma unroll
    for (int tj = 0; tj < 4; ++tj) {
      int d = dbase + tj * 16 + r;
#pragma unroll
      for (int v = 0; v < 4; ++v) {
        int i = ibase + ti * 16 + (lane >> 4) * 4 + v;
        Ob[(size_t)i * DD + d] = acc[ti][tj][v];
      }
    }
  }
}

// ---------------------------------------------------------------------------
extern "C" void kernel_launch(void* const* d_in, const int* in_sizes, int n_in,
                              void* d_out, int out_size, void* d_ws, size_t ws_size,
                              hipStream_t stream) {
  const float* text  = (const float*)d_in[0];
  const float* audio = (const float*)d_in[1];
  const float* sigma = (const float*)d_in[2];
  const int*   lens  = (const int*)d_in[3];

  float* out = (float*)d_out;
  float* enhanced = out;                       // B*N*D fp32
  float* attn = out + (size_t)BB * NN * DD;    // B*N*M fp32

  const size_t QBF  = (size_t)BB * NN * DD * 2;   // 16 MB
  const size_t KBF  = (size_t)BB * MM * DD * 2;   // 32 MB
  const size_t VTB  = (size_t)BB * DD * MM * 2;   // 32 MB
  const size_t EBF  = (size_t)BB * NN * MM * 2;   // 32 MB
  const size_t offQ = 65536;
  const size_t offK = offQ + QBF;
  const size_t offV = offK + KBF;
  const size_t offE = offV + VTB;
  const size_t need = offE + EBF;

  float* rowsum = (float*)d_ws;                // 32 KB @ 0

  if (ws_size >= need) {
    unsigned short* Qbf = (unsigned short*)((char*)d_ws + offQ);
    unsigned short* Kbf = (unsigned short*)((char*)d_ws + offK);
    unsigned short* VT  = (unsigned short*)((char*)d_ws + offV);
    unsigned short* Ebf = (unsigned short*)((char*)d_ws + offE);

    ta_prep<<<dim3(8224), 256, 0, stream>>>(text, audio, Qbf, Kbf, VT, rowsum);
    ta_gemm1x<<<dim3(MM / 256, NN / 256, BB), 512, 0, stream>>>(Qbf, Kbf, sigma, lens, Ebf, rowsum);
    ta_gemm2x<<<dim3(DD / 256, NN / 128, BB), 512, 0, stream>>>(Ebf, VT, rowsum, enhanced, attn);
  } else {
    ta_zero<<<dim3((BB * NN + 255) / 256), 256, 0, stream>>>(rowsum);
    tb_gemm1e<<<dim3(MM / 128, NN / 128, BB), 256, 0, stream>>>(text, audio, sigma, lens, attn, rowsum);
    tb_norm<<<dim3(BB * NN * MM / 4 / 256), 256, 0, stream>>>(attn, rowsum);
    tb_gemm2<<<dim3(DD / 128, NN / 128, BB), 256, 0, stream>>>(attn, audio, enhanced);
  }
}